// Round 1
// 826.036 us; speedup vs baseline: 1.0888x; 1.0888x over previous
//
#include <hip/hip_runtime.h>
#include <cmath>

// Problem constants: B=32, T=512, S=1024, D=1024
#define BATCH 32
#define TLEN  512
#define SLEN  1024
#define DIM   1024

#define BM 128
#define BN 128
#define BK 32

typedef _Float16 h8 __attribute__((ext_vector_type(8)));
typedef _Float16 h4 __attribute__((ext_vector_type(4)));
typedef _Float16 h2 __attribute__((ext_vector_type(2)));
typedef float f4 __attribute__((ext_vector_type(4)));

// ---------------------------------------------------------------------------
// NEW FAST PATH: pure-fp16 NT GEMM, m97 structure (global_load_lds width=16).
// ---------------------------------------------------------------------------

__device__ __forceinline__ void gload16(const _Float16* g, _Float16* l) {
  __builtin_amdgcn_global_load_lds(
      (const __attribute__((address_space(1))) unsigned int*)g,
      (__attribute__((address_space(3))) unsigned int*)l, 16, 0, 0);
}

// C[m,n] = sum_k A[m,k] * B[n,k]   (both operands fp16, k-contiguous rows)
// EPI: 0 = f32 store, 1 = f32 tanh store, 2 = f16 store, 3 = f32 + f16 store
template <int EPI>
__global__ __launch_bounds__(256) void gemm16(
    const _Float16* __restrict__ A, const _Float16* __restrict__ Bm,
    float* __restrict__ C, _Float16* __restrict__ C16, int K,
    long lda, long ldb, long ldc, long ldc16,
    long strideA, long strideB, long strideC, long strideC16) {
  __shared__ _Float16 As[BM * BK];  // 8 KiB, linear [row][k] — matches
  __shared__ _Float16 Bs[BN * BK];  // global_load_lds lane-linear writes

  const int bz = blockIdx.z;
  A += (long)bz * strideA;
  Bm += (long)bz * strideB;

  const int m0 = blockIdx.y * BM;
  const int n0 = blockIdx.x * BN;
  const int tid = threadIdx.x;
  const int lane = tid & 63;
  const int wave = tid >> 6;
  const int q = lane >> 4;   // k-quad 0..3
  const int r = lane & 15;   // row/col within 16
  const int wm = (wave >> 1) * 64;
  const int wn = (wave & 1) * 64;

  f4 acc[4][4];
#pragma unroll
  for (int i = 0; i < 4; ++i)
#pragma unroll
    for (int j = 0; j < 4; ++j) acc[i][j] = (f4){0.f, 0.f, 0.f, 0.f};

  // Tile = 512 chunks of 16B (row = c>>2, k-offset = (c&3)*8 halfs).
  // Wave w, issue i covers chunks [(i*4+w)*64, +64): LDS dest is the
  // wave-uniform base + lane*16 that global_load_lds requires.
  const int c0 = wave * 64 + lane;
  const int c1 = 256 + wave * 64 + lane;
  const _Float16* gA0 = A + (long)(m0 + (c0 >> 2)) * lda + (c0 & 3) * 8;
  const _Float16* gA1 = A + (long)(m0 + (c1 >> 2)) * lda + (c1 & 3) * 8;
  const _Float16* gB0 = Bm + (long)(n0 + (c0 >> 2)) * ldb + (c0 & 3) * 8;
  const _Float16* gB1 = Bm + (long)(n0 + (c1 >> 2)) * ldb + (c1 & 3) * 8;
  _Float16* lA0 = As + wave * 512;
  _Float16* lA1 = As + 2048 + wave * 512;
  _Float16* lB0 = Bs + wave * 512;
  _Float16* lB1 = Bs + 2048 + wave * 512;

  for (int k0 = 0; k0 < K; k0 += BK) {
    gload16(gA0 + k0, lA0);
    gload16(gA1 + k0, lA1);
    gload16(gB0 + k0, lB0);
    gload16(gB1 + k0, lB1);
    __syncthreads();  // compiler emits vmcnt(0) drain — m97 structure

    h8 av[4], bv[4];
#pragma unroll
    for (int mt = 0; mt < 4; ++mt)
      av[mt] = *(const h8*)&As[(wm + mt * 16 + r) * BK + q * 8];
#pragma unroll
    for (int nt = 0; nt < 4; ++nt)
      bv[nt] = *(const h8*)&Bs[(wn + nt * 16 + r) * BK + q * 8];
#pragma unroll
    for (int mt = 0; mt < 4; ++mt)
#pragma unroll
      for (int nt = 0; nt < 4; ++nt)
        acc[mt][nt] = __builtin_amdgcn_mfma_f32_16x16x32_f16(
            av[mt], bv[nt], acc[mt][nt], 0, 0, 0);
    __syncthreads();
  }

  // epilogue: D[row=(q*4+i)][col=r] per 16x16 tile (verified layout)
#pragma unroll
  for (int mt = 0; mt < 4; ++mt) {
#pragma unroll
    for (int nt = 0; nt < 4; ++nt) {
#pragma unroll
      for (int i = 0; i < 4; ++i) {
        float x = acc[mt][nt][i];
        const long row = m0 + wm + mt * 16 + q * 4 + i;
        const long col = n0 + wn + nt * 16 + r;
        if constexpr (EPI == 1) x = tanhf(x);
        if constexpr (EPI == 0 || EPI == 1 || EPI == 3)
          C[(long)bz * strideC + row * ldc + col] = x;
        if constexpr (EPI == 2 || EPI == 3)
          C16[(long)bz * strideC16 + row * ldc16 + col] = (_Float16)x;
      }
    }
  }
}

// Generic fp32 -> fp16 convert (memory-bound, float4 in / h4 out).
__global__ __launch_bounds__(256) void cvt_f32_f16(
    const float* __restrict__ in, _Float16* __restrict__ out, long n) {
  long i = ((long)blockIdx.x * 256 + threadIdx.x) * 4;
  const long stride = (long)gridDim.x * 1024;
  for (; i < n; i += stride) {
    float4 v = *(const float4*)(in + i);
    h4 hv = {(_Float16)v.x, (_Float16)v.y, (_Float16)v.z, (_Float16)v.w};
    *(h4*)(out + i) = hv;
  }
}

// context [B,S,D] fp32 -> c16 [B,S,D] fp16 + c16t [B,D,S] fp16 (transposed).
#define CTPAD 66  // odd-ish word stride -> ~2-way on the gather reads
__global__ __launch_bounds__(256) void ctx_cvt(
    const float* __restrict__ ctx, _Float16* __restrict__ c16,
    _Float16* __restrict__ c16t) {
  __shared__ _Float16 tile[64 * CTPAD];
  const int b = blockIdx.z;
  const int s0 = blockIdx.y * 64;
  const int d0 = blockIdx.x * 64;
  const int tr = threadIdx.x >> 4;        // 0..15
  const int tc = (threadIdx.x & 15) * 4;  // 0..60
#pragma unroll
  for (int i = 0; i < 4; ++i) {
    const int s = i * 16 + tr;
    float4 v = *(const float4*)(ctx + ((long)b * SLEN + s0 + s) * DIM + d0 + tc);
    h4 hv = {(_Float16)v.x, (_Float16)v.y, (_Float16)v.z, (_Float16)v.w};
    *(h4*)(c16 + ((long)b * SLEN + s0 + s) * DIM + d0 + tc) = hv;
    tile[s * CTPAD + tc] = hv.x;
    tile[s * CTPAD + tc + 1] = hv.y;
    tile[s * CTPAD + tc + 2] = hv.z;
    tile[s * CTPAD + tc + 3] = hv.w;
  }
  __syncthreads();
#pragma unroll
  for (int i = 0; i < 4; ++i) {
    const int d = i * 16 + tr;
    h4 hv = {tile[tc * CTPAD + d], tile[(tc + 1) * CTPAD + d],
             tile[(tc + 2) * CTPAD + d], tile[(tc + 3) * CTPAD + d]};
    *(h4*)(c16t + ((long)b * DIM + d0 + d) * SLEN + s0 + tc) = hv;
  }
}

// ---------------------------------------------------------------------------
// FALLBACK PATH (previous verified kernel): fp32-operand convert-at-staging.
// ---------------------------------------------------------------------------

#define AS_LD 40   // BK + 8 pad halfs
#define B2_LD 134  // BN + 6 pad halfs

template <bool B_IS_NT, bool TANH>
__global__ __launch_bounds__(256) void gemm_f16(
    const float* __restrict__ A, const float* __restrict__ Bm,
    float* __restrict__ C, int M, int N, int K, long lda, long ldb, long ldc,
    long strideA, long strideB, long strideC) {
  __shared__ _Float16 As[BM * AS_LD];
  __shared__ _Float16 Bs[BM * AS_LD];

  const int bz = blockIdx.z;
  A += (long)bz * strideA;
  Bm += (long)bz * strideB;
  C += (long)bz * strideC;

  const int m0 = blockIdx.y * BM;
  const int n0 = blockIdx.x * BN;
  const int tid = threadIdx.x;
  const int lane = tid & 63;
  const int wave = tid >> 6;
  const int wm = (wave >> 1) * 64;
  const int wn = (wave & 1) * 64;
  const int q = lane >> 4;
  const int r = lane & 15;

  f4 acc[4][4];
#pragma unroll
  for (int i = 0; i < 4; ++i)
#pragma unroll
    for (int j = 0; j < 4; ++j) acc[i][j] = (f4){0.f, 0.f, 0.f, 0.f};

  const int srow = tid >> 3;
  const int skq = (tid & 7) * 4;
  const int nrow = tid >> 5;
  const int nnq = (tid & 31) * 4;

  for (int k0 = 0; k0 < K; k0 += BK) {
#pragma unroll
    for (int it = 0; it < 4; ++it) {
      const int row = it * 32 + srow;
      f4 v = *(const f4*)(A + (long)(m0 + row) * lda + k0 + skq);
      h4 hv = {(_Float16)v.x, (_Float16)v.y, (_Float16)v.z, (_Float16)v.w};
      *(h4*)&As[row * AS_LD + skq] = hv;
    }
    if (B_IS_NT) {
#pragma unroll
      for (int it = 0; it < 4; ++it) {
        const int row = it * 32 + srow;
        f4 v = *(const f4*)(Bm + (long)(n0 + row) * ldb + k0 + skq);
        h4 hv = {(_Float16)v.x, (_Float16)v.y, (_Float16)v.z, (_Float16)v.w};
        *(h4*)&Bs[row * AS_LD + skq] = hv;
      }
    } else {
#pragma unroll
      for (int it = 0; it < 4; ++it) {
        const int krow = it * 8 + nrow;
        f4 v = *(const f4*)(Bm + (long)(k0 + krow) * ldb + n0 + nnq);
        _Float16* p = &Bs[krow * B2_LD + nnq];
        *(h2*)p = (h2){(_Float16)v.x, (_Float16)v.y};
        *(h2*)(p + 2) = (h2){(_Float16)v.z, (_Float16)v.w};
      }
    }
    __syncthreads();

    h8 av[4], bv[4];
#pragma unroll
    for (int mt = 0; mt < 4; ++mt)
      av[mt] = *(const h8*)&As[(wm + mt * 16 + r) * AS_LD + q * 8];
    if (B_IS_NT) {
#pragma unroll
      for (int nt = 0; nt < 4; ++nt)
        bv[nt] = *(const h8*)&Bs[(wn + nt * 16 + r) * AS_LD + q * 8];
    } else {
#pragma unroll
      for (int nt = 0; nt < 4; ++nt) {
        h8 t;
#pragma unroll
        for (int j = 0; j < 8; ++j)
          t[j] = Bs[(q * 8 + j) * B2_LD + wn + nt * 16 + r];
        bv[nt] = t;
      }
    }
#pragma unroll
    for (int mt = 0; mt < 4; ++mt)
#pragma unroll
      for (int nt = 0; nt < 4; ++nt)
        acc[mt][nt] = __builtin_amdgcn_mfma_f32_16x16x32_f16(
            av[mt], bv[nt], acc[mt][nt], 0, 0, 0);
    __syncthreads();
  }

#pragma unroll
  for (int mt = 0; mt < 4; ++mt) {
#pragma unroll
    for (int nt = 0; nt < 4; ++nt) {
#pragma unroll
      for (int i = 0; i < 4; ++i) {
        float x = acc[mt][nt][i];
        if (TANH) x = tanhf(x);
        C[(long)(m0 + wm + mt * 16 + q * 4 + i) * ldc + n0 + wn + nt * 16 + r] = x;
      }
    }
  }
}

// ---------------------------------------------------------------------------
// Shared auxiliary kernels
// ---------------------------------------------------------------------------

// In-place softmax over rows of length 1024; optional fp16 dual-write.
__global__ __launch_bounds__(256) void softmax_kernel(
    float* __restrict__ data, _Float16* __restrict__ p16) {
  float* row = data + (long)blockIdx.x * SLEN;
  const int tid = threadIdx.x;
  float4 v = ((float4*)row)[tid];
  float m = fmaxf(fmaxf(v.x, v.y), fmaxf(v.z, v.w));
#pragma unroll
  for (int off = 32; off > 0; off >>= 1) m = fmaxf(m, __shfl_xor(m, off));
  __shared__ float redm[4];
  __shared__ float reds[4];
  if ((tid & 63) == 0) redm[tid >> 6] = m;
  __syncthreads();
  m = fmaxf(fmaxf(redm[0], redm[1]), fmaxf(redm[2], redm[3]));
  v.x = expf(v.x - m);
  v.y = expf(v.y - m);
  v.z = expf(v.z - m);
  v.w = expf(v.w - m);
  float s = v.x + v.y + v.z + v.w;
#pragma unroll
  for (int off = 32; off > 0; off >>= 1) s += __shfl_xor(s, off);
  if ((tid & 63) == 0) reds[tid >> 6] = s;
  __syncthreads();
  s = reds[0] + reds[1] + reds[2] + reds[3];
  const float inv = 1.0f / s;
  v.x *= inv;
  v.y *= inv;
  v.z *= inv;
  v.w *= inv;
  ((float4*)row)[tid] = v;
  if (p16) {
    h4 hv = {(_Float16)v.x, (_Float16)v.y, (_Float16)v.z, (_Float16)v.w};
    *(h4*)(p16 + (long)blockIdx.x * SLEN + tid * 4) = hv;
  }
}

// concat[t, b, DIM + d] = input[b, t, d]; optional fp16 dual-write.
__global__ __launch_bounds__(256) void concat_copy_kernel(
    const float* __restrict__ in, float* __restrict__ concat,
    _Float16* __restrict__ c16) {
  const int bt = blockIdx.x;  // b*T + t
  const int b = bt >> 9;      // T = 512
  const int t = bt & 511;
  const float4 v = ((const float4*)(in + (long)bt * DIM))[threadIdx.x];
  const long off = ((long)t * BATCH + b) * (2 * DIM) + DIM;
  ((float4*)(concat + off))[threadIdx.x] = v;
  if (c16) {
    h4 hv = {(_Float16)v.x, (_Float16)v.y, (_Float16)v.z, (_Float16)v.w};
    *(h4*)(c16 + off + threadIdx.x * 4) = hv;
  }
}

// ---------------------------------------------------------------------------

extern "C" void kernel_launch(void* const* d_in, const int* in_sizes, int n_in,
                              void* d_out, int out_size, void* d_ws,
                              size_t ws_size, hipStream_t stream) {
  const float* input = (const float*)d_in[0];    // [B,T,D]
  const float* context = (const float*)d_in[1];  // [B,S,D]
  const float* W_in = (const float*)d_in[2];     // [D,D]
  const float* W_out = (const float*)d_in[3];    // [D,2D]

  float* out = (float*)d_out;
  float* attn_h = out;                                // [T,B,D]
  float* align = out + (long)TLEN * BATCH * DIM;      // [T,B,S]
  float* concat = align + (long)TLEN * BATCH * SLEN;  // [T,B,2D]

  const long BT = (long)BATCH * TLEN;  // 16384
  const long ND = (long)BATCH * TLEN * DIM;  // 16,777,216 elements

  // ws: ctx16 (64 MiB) + ctx16t (64 MiB) + cat16 (64 MiB) + wout16 (4 MiB)
  const size_t WS_NEED = (size_t)3 * 67108864 + 4194304;

  if (d_ws != nullptr && ws_size >= WS_NEED) {
    _Float16* ctx16 = (_Float16*)d_ws;                  // [B,S,D]
    _Float16* ctx16t = ctx16 + (long)BATCH * SLEN * DIM;  // [B,D,S]
    _Float16* cat16 = ctx16t + (long)BATCH * SLEN * DIM;  // [T,B,2D]
    _Float16* wout16 = cat16 + (long)TLEN * BATCH * 2 * DIM;  // [D,2D]
    // Carved scratch: align region is dead until GEMM2 writes it;
    // attn_h region is dead until GEMM4's epilogue.
    _Float16* in16 = (_Float16*)align;      // [B,T,D], dies after GEMM1
    _Float16* win16 = in16 + ND;            // [D,D],   dies after GEMM1
    _Float16* ht16 = (_Float16*)attn_h;     // [B,T,D], dies after GEMM2
    _Float16* p16 = ht16 + ND;              // [T,B,S], dies after GEMM3

    cvt_f32_f16<<<2048, 256, 0, stream>>>(input, in16, ND);
    cvt_f32_f16<<<1024, 256, 0, stream>>>(W_in, win16, (long)DIM * DIM);
    cvt_f32_f16<<<2048, 256, 0, stream>>>(W_out, wout16, (long)DIM * 2 * DIM);
    ctx_cvt<<<dim3(16, 16, BATCH), 256, 0, stream>>>(context, ctx16, ctx16t);

    // GEMM1 (f16 out): ht16[b*T+t, e] = sum_d in16[bt,d] * win16[e,d]
    gemm16<2><<<dim3(DIM / BN, BT / BM, 1), 256, 0, stream>>>(
        in16, win16, nullptr, ht16, DIM,
        /*lda*/ DIM, /*ldb*/ DIM, /*ldc*/ 0, /*ldc16*/ DIM, 0, 0, 0, 0);

    // GEMM2 (f32 out, batched): align[t,b,s] = sum_d ht16[b,t,d]*ctx16[b,s,d]
    gemm16<0><<<dim3(SLEN / BN, TLEN / BM, BATCH), 256, 0, stream>>>(
        ht16, ctx16, align, nullptr, DIM,
        /*lda*/ DIM, /*ldb*/ DIM, /*ldc*/ (long)BATCH * SLEN, /*ldc16*/ 0,
        /*sA*/ (long)TLEN * DIM, /*sB*/ (long)SLEN * DIM, /*sC*/ SLEN, 0);

    softmax_kernel<<<(int)BT, 256, 0, stream>>>(align, p16);

    // GEMM3 (f32+f16 out, batched): c[t,b,d] = sum_s p16[t,b,s]*ctx16t[b,d,s]
    gemm16<3><<<dim3(DIM / BN, TLEN / BM, BATCH), 256, 0, stream>>>(
        p16, ctx16t, concat, cat16, SLEN,
        /*lda*/ (long)BATCH * SLEN, /*ldb*/ SLEN,
        /*ldc*/ (long)BATCH * 2 * DIM, /*ldc16*/ (long)BATCH * 2 * DIM,
        /*sA*/ SLEN, /*sB*/ (long)DIM * SLEN, /*sC*/ 2 * DIM, /*sC16*/ 2 * DIM);

    concat_copy_kernel<<<(int)BT, 256, 0, stream>>>(input, concat, cat16);

    // GEMM4 (f32 + tanh): attn_h[t*B+b, d] = tanh(sum_f cat16[tb,f]*wout16[d,f])
    gemm16<1><<<dim3(DIM / BN, BT / BM, 1), 256, 0, stream>>>(
        cat16, wout16, attn_h, nullptr, 2 * DIM,
        /*lda*/ 2 * DIM, /*ldb*/ 2 * DIM, /*ldc*/ DIM, /*ldc16*/ 0, 0, 0, 0, 0);
    return;
  }

  // -------- fallback: previous verified fp32-operand pipeline --------
  float* h_t = attn_h;

  gemm_f16<true, false><<<dim3(DIM / BN, BT / BM, 1), 256, 0, stream>>>(
      input, W_in, h_t, (int)BT, DIM, DIM, DIM, DIM, DIM, 0, 0, 0);

  gemm_f16<true, false><<<dim3(SLEN / BN, TLEN / BM, BATCH), 256, 0, stream>>>(
      h_t, context, align, TLEN, SLEN, DIM, DIM, DIM, (long)BATCH * SLEN,
      (long)TLEN * DIM, (long)SLEN * DIM, SLEN);

  softmax_kernel<<<(int)BT, 256, 0, stream>>>(align, nullptr);

  gemm_f16<false, false><<<dim3(DIM / BN, TLEN / BM, BATCH), 256, 0, stream>>>(
      align, context, concat, TLEN, DIM, SLEN, (long)BATCH * SLEN, DIM,
      (long)BATCH * 2 * DIM, SLEN, (long)SLEN * DIM, 2 * DIM);

  concat_copy_kernel<<<(int)BT, 256, 0, stream>>>(input, concat, nullptr);

  gemm_f16<true, true><<<dim3(DIM / BN, BT / BM, 1), 256, 0, stream>>>(
      concat, W_out, attn_h, (int)BT, DIM, 2 * DIM, 2 * DIM, 2 * DIM, DIM,
      0, 0, 0);
}

// Round 2
// 765.367 us; speedup vs baseline: 1.1751x; 1.0793x over previous
//
#include <hip/hip_runtime.h>
#include <cmath>

// Problem constants: B=32, T=512, S=1024, D=1024
#define BATCH 32
#define TLEN  512
#define SLEN  1024
#define DIM   1024

#define BM 128
#define BN 128
#define BK2 64

typedef _Float16 h8 __attribute__((ext_vector_type(8)));
typedef _Float16 h4 __attribute__((ext_vector_type(4)));
typedef _Float16 h2 __attribute__((ext_vector_type(2)));
typedef float f4 __attribute__((ext_vector_type(4)));

// ---------------------------------------------------------------------------
// FAST PATH: pure-fp16 NT GEMM, m97 structure + BK=64 + T2 swizzle.
// ---------------------------------------------------------------------------

__device__ __forceinline__ void gload16(const _Float16* g, _Float16* l) {
  __builtin_amdgcn_global_load_lds(
      (const __attribute__((address_space(1))) unsigned int*)g,
      (__attribute__((address_space(3))) unsigned int*)l, 16, 0, 0);
}

// C[m,n] = sum_k A[m,k] * B[n,k]   (both operands fp16, k-contiguous rows)
// EPI: 0=f32, 1=f32 tanh, 2=f16, 3=f32+f16, 4=f32+f16 + concat-copy fold
template <int EPI>
__global__ __launch_bounds__(256) void gemm16(
    const _Float16* __restrict__ A, const _Float16* __restrict__ Bm,
    float* __restrict__ C, _Float16* __restrict__ C16, int K,
    long lda, long ldb, long ldc, long ldc16,
    long strideA, long strideB, long strideC, long strideC16,
    const float* __restrict__ Xin) {
  // Linear [row][64] halfs, 128B rows. Content is stored with the inverse
  // swizzle at the SOURCE (global addr), read with chunk^=(row&7) -> the
  // ds_read_b128 pattern is bank-conflict-free (rule #21: both-sides swz).
  __shared__ _Float16 As[BM * BK2];  // 16 KiB
  __shared__ _Float16 Bs[BM * BK2];  // 16 KiB

  const int bz = blockIdx.z;
  A += (long)bz * strideA;
  Bm += (long)bz * strideB;

  const int m0 = blockIdx.y * BM;
  const int n0 = blockIdx.x * BN;
  const int tid = threadIdx.x;
  const int lane = tid & 63;
  const int wave = tid >> 6;
  const int q = lane >> 4;   // k-quad 0..3
  const int r = lane & 15;   // row/col within 16
  const int wm = (wave >> 1) * 64;
  const int wn = (wave & 1) * 64;

  f4 acc[4][4];
#pragma unroll
  for (int i = 0; i < 4; ++i)
#pragma unroll
    for (int j = 0; j < 4; ++j) acc[i][j] = (f4){0.f, 0.f, 0.f, 0.f};

  // Staging: tile = 1024 chunks of 16B; 4 issues/thread/operand.
  // chunk c: row = c>>3, in-row chunk j = c&7; SOURCE swizzle j' = j^(row&7).
  const _Float16* gA[4];
  const _Float16* gB[4];
  _Float16* lA[4];
  _Float16* lB[4];
#pragma unroll
  for (int i = 0; i < 4; ++i) {
    const int c = i * 256 + tid;
    const int row = c >> 3;
    const int j = (c & 7) ^ (row & 7);
    gA[i] = A + (long)(m0 + row) * lda + j * 8;
    gB[i] = Bm + (long)(n0 + row) * ldb + j * 8;
    lA[i] = As + i * 2048 + wave * 512;  // wave-uniform base + lane*16B (HW)
    lB[i] = Bs + i * 2048 + wave * 512;
  }

  for (int k0 = 0; k0 < K; k0 += BK2) {
#pragma unroll
    for (int i = 0; i < 4; ++i) gload16(gA[i] + k0, lA[i]);
#pragma unroll
    for (int i = 0; i < 4; ++i) gload16(gB[i] + k0, lB[i]);
    __syncthreads();

#pragma unroll
    for (int kk = 0; kk < 2; ++kk) {
      h8 av[4], bv[4];
#pragma unroll
      for (int mt = 0; mt < 4; ++mt) {
        const int row = wm + mt * 16 + r;
        const int u = (kk * 4 + q) ^ (r & 7);  // read-side swizzle
        av[mt] = *(const h8*)&As[row * BK2 + u * 8];
      }
#pragma unroll
      for (int nt = 0; nt < 4; ++nt) {
        const int row = wn + nt * 16 + r;
        const int u = (kk * 4 + q) ^ (r & 7);
        bv[nt] = *(const h8*)&Bs[row * BK2 + u * 8];
      }
#pragma unroll
      for (int mt = 0; mt < 4; ++mt)
#pragma unroll
        for (int nt = 0; nt < 4; ++nt)
          acc[mt][nt] = __builtin_amdgcn_mfma_f32_16x16x32_f16(
              av[mt], bv[nt], acc[mt][nt], 0, 0, 0);
    }
    __syncthreads();
  }

  // epilogue: D[row=(q*4+i)][col=r] per 16x16 tile (verified layout)
#pragma unroll
  for (int mt = 0; mt < 4; ++mt) {
#pragma unroll
    for (int nt = 0; nt < 4; ++nt) {
#pragma unroll
      for (int i = 0; i < 4; ++i) {
        float x = acc[mt][nt][i];
        const long row = m0 + wm + mt * 16 + q * 4 + i;
        const long col = n0 + wn + nt * 16 + r;
        if constexpr (EPI == 1) x = tanhf(x);
        if constexpr (EPI != 2)
          C[(long)bz * strideC + row * ldc + col] = x;
        if constexpr (EPI >= 2)
          C16[(long)bz * strideC16 + row * ldc16 + col] = (_Float16)x;
      }
    }
  }

  if constexpr (EPI == 4) {
    // Fold of concat_copy: concat[t, b, DIM + d] = input[b, t, d] (f32+f16).
    // Block covers rows m0..m0+127 (t), cols n0..n0+127 (d), batch bz.
#pragma unroll
    for (int it = 0; it < 16; ++it) {
      const int idx = it * 256 + tid;
      const int row = idx >> 5;          // 32 f4-chunks per 128-col row
      const int c4 = (idx & 31) * 4;
      const f4 v = *(const f4*)(Xin + ((long)bz * TLEN + m0 + row) * DIM +
                                n0 + c4);
      const long off = (long)bz * strideC + (long)(m0 + row) * ldc + DIM +
                       n0 + c4;
      *(f4*)(C + off) = v;
      h4 hv = {(_Float16)v.x, (_Float16)v.y, (_Float16)v.z, (_Float16)v.w};
      *(h4*)(C16 + (long)bz * strideC16 + (long)(m0 + row) * ldc16 + DIM +
             n0 + c4) = hv;
    }
  }
}

// One-launch fp32->fp16 convert of input + W_in + W_out (block-range split).
__global__ __launch_bounds__(256) void cvt3(
    const float* __restrict__ in, _Float16* __restrict__ out,
    const float* __restrict__ in2, _Float16* __restrict__ out2,
    const float* __restrict__ in3, _Float16* __restrict__ out3) {
  const int b = blockIdx.x;
  const float* src;
  _Float16* dst;
  long n;
  int b0, nb;
  if (b < 384) { src = in;  dst = out;  n = 16777216; b0 = 0;   nb = 384; }
  else if (b < 408) { src = in2; dst = out2; n = 1048576; b0 = 384; nb = 24; }
  else { src = in3; dst = out3; n = 2097152; b0 = 408; nb = 48; }
  long i = ((long)(b - b0) * 256 + threadIdx.x) * 4;
  const long stride = (long)nb * 1024;
  for (; i < n; i += stride) {
    f4 v = *(const f4*)(src + i);
    h4 hv = {(_Float16)v.x, (_Float16)v.y, (_Float16)v.z, (_Float16)v.w};
    *(h4*)(dst + i) = hv;
  }
}

// context [B,S,D] fp32 -> c16 [B,S,D] fp16 + c16t [B,D,S] fp16 (transposed).
#define CTPAD 68  // multiple of 4 (h4-aligned LDS writes)
__global__ __launch_bounds__(256) void ctx_cvt(
    const float* __restrict__ ctx, _Float16* __restrict__ c16,
    _Float16* __restrict__ c16t) {
  __shared__ _Float16 tile[64 * CTPAD];
  const int b = blockIdx.z;
  const int s0 = blockIdx.y * 64;
  const int d0 = blockIdx.x * 64;
  const int tr = threadIdx.x >> 4;        // 0..15
  const int tc = (threadIdx.x & 15) * 4;  // 0..60
#pragma unroll
  for (int i = 0; i < 4; ++i) {
    const int s = i * 16 + tr;
    float4 v = *(const float4*)(ctx + ((long)b * SLEN + s0 + s) * DIM + d0 + tc);
    h4 hv = {(_Float16)v.x, (_Float16)v.y, (_Float16)v.z, (_Float16)v.w};
    *(h4*)(c16 + ((long)b * SLEN + s0 + s) * DIM + d0 + tc) = hv;
    *(h4*)&tile[s * CTPAD + tc] = hv;
  }
  __syncthreads();
#pragma unroll
  for (int i = 0; i < 4; ++i) {
    const int d = i * 16 + tr;
    h4 hv = {tile[tc * CTPAD + d], tile[(tc + 1) * CTPAD + d],
             tile[(tc + 2) * CTPAD + d], tile[(tc + 3) * CTPAD + d]};
    *(h4*)(c16t + ((long)b * DIM + d0 + d) * SLEN + s0 + tc) = hv;
  }
}

// ---------------------------------------------------------------------------
// FALLBACK PATH (verified round-0 kernel): fp32-operand convert-at-staging.
// ---------------------------------------------------------------------------

#define AS_LD 40   // BK + 8 pad halfs
#define B2_LD 134  // BN + 6 pad halfs
#define BKF 32

template <bool B_IS_NT, bool TANH>
__global__ __launch_bounds__(256) void gemm_f16(
    const float* __restrict__ A, const float* __restrict__ Bm,
    float* __restrict__ C, int M, int N, int K, long lda, long ldb, long ldc,
    long strideA, long strideB, long strideC) {
  __shared__ _Float16 As[BM * AS_LD];
  __shared__ _Float16 Bs[BM * AS_LD];

  const int bz = blockIdx.z;
  A += (long)bz * strideA;
  Bm += (long)bz * strideB;
  C += (long)bz * strideC;

  const int m0 = blockIdx.y * BM;
  const int n0 = blockIdx.x * BN;
  const int tid = threadIdx.x;
  const int lane = tid & 63;
  const int wave = tid >> 6;
  const int wm = (wave >> 1) * 64;
  const int wn = (wave & 1) * 64;
  const int q = lane >> 4;
  const int r = lane & 15;

  f4 acc[4][4];
#pragma unroll
  for (int i = 0; i < 4; ++i)
#pragma unroll
    for (int j = 0; j < 4; ++j) acc[i][j] = (f4){0.f, 0.f, 0.f, 0.f};

  const int srow = tid >> 3;
  const int skq = (tid & 7) * 4;
  const int nrow = tid >> 5;
  const int nnq = (tid & 31) * 4;

  for (int k0 = 0; k0 < K; k0 += BKF) {
#pragma unroll
    for (int it = 0; it < 4; ++it) {
      const int row = it * 32 + srow;
      f4 v = *(const f4*)(A + (long)(m0 + row) * lda + k0 + skq);
      h4 hv = {(_Float16)v.x, (_Float16)v.y, (_Float16)v.z, (_Float16)v.w};
      *(h4*)&As[row * AS_LD + skq] = hv;
    }
    if (B_IS_NT) {
#pragma unroll
      for (int it = 0; it < 4; ++it) {
        const int row = it * 32 + srow;
        f4 v = *(const f4*)(Bm + (long)(n0 + row) * ldb + k0 + skq);
        h4 hv = {(_Float16)v.x, (_Float16)v.y, (_Float16)v.z, (_Float16)v.w};
        *(h4*)&Bs[row * AS_LD + skq] = hv;
      }
    } else {
#pragma unroll
      for (int it = 0; it < 4; ++it) {
        const int krow = it * 8 + nrow;
        f4 v = *(const f4*)(Bm + (long)(k0 + krow) * ldb + n0 + nnq);
        _Float16* p = &Bs[krow * B2_LD + nnq];
        *(h2*)p = (h2){(_Float16)v.x, (_Float16)v.y};
        *(h2*)(p + 2) = (h2){(_Float16)v.z, (_Float16)v.w};
      }
    }
    __syncthreads();

    h8 av[4], bv[4];
#pragma unroll
    for (int mt = 0; mt < 4; ++mt)
      av[mt] = *(const h8*)&As[(wm + mt * 16 + r) * AS_LD + q * 8];
    if (B_IS_NT) {
#pragma unroll
      for (int nt = 0; nt < 4; ++nt)
        bv[nt] = *(const h8*)&Bs[(wn + nt * 16 + r) * AS_LD + q * 8];
    } else {
#pragma unroll
      for (int nt = 0; nt < 4; ++nt) {
        h8 t;
#pragma unroll
        for (int j = 0; j < 8; ++j)
          t[j] = Bs[(q * 8 + j) * B2_LD + wn + nt * 16 + r];
        bv[nt] = t;
      }
    }
#pragma unroll
    for (int mt = 0; mt < 4; ++mt)
#pragma unroll
      for (int nt = 0; nt < 4; ++nt)
        acc[mt][nt] = __builtin_amdgcn_mfma_f32_16x16x32_f16(
            av[mt], bv[nt], acc[mt][nt], 0, 0, 0);
    __syncthreads();
  }

#pragma unroll
  for (int mt = 0; mt < 4; ++mt) {
#pragma unroll
    for (int nt = 0; nt < 4; ++nt) {
#pragma unroll
      for (int i = 0; i < 4; ++i) {
        float x = acc[mt][nt][i];
        if (TANH) x = tanhf(x);
        C[(long)(m0 + wm + mt * 16 + q * 4 + i) * ldc + n0 + wn + nt * 16 + r] = x;
      }
    }
  }
}

// ---------------------------------------------------------------------------
// Shared auxiliary kernels
// ---------------------------------------------------------------------------

// In-place softmax over rows of length 1024; optional fp16 dual-write.
__global__ __launch_bounds__(256) void softmax_kernel(
    float* __restrict__ data, _Float16* __restrict__ p16) {
  float* row = data + (long)blockIdx.x * SLEN;
  const int tid = threadIdx.x;
  float4 v = ((float4*)row)[tid];
  float m = fmaxf(fmaxf(v.x, v.y), fmaxf(v.z, v.w));
#pragma unroll
  for (int off = 32; off > 0; off >>= 1) m = fmaxf(m, __shfl_xor(m, off));
  __shared__ float redm[4];
  __shared__ float reds[4];
  if ((tid & 63) == 0) redm[tid >> 6] = m;
  __syncthreads();
  m = fmaxf(fmaxf(redm[0], redm[1]), fmaxf(redm[2], redm[3]));
  v.x = expf(v.x - m);
  v.y = expf(v.y - m);
  v.z = expf(v.z - m);
  v.w = expf(v.w - m);
  float s = v.x + v.y + v.z + v.w;
#pragma unroll
  for (int off = 32; off > 0; off >>= 1) s += __shfl_xor(s, off);
  if ((tid & 63) == 0) reds[tid >> 6] = s;
  __syncthreads();
  s = reds[0] + reds[1] + reds[2] + reds[3];
  const float inv = 1.0f / s;
  v.x *= inv;
  v.y *= inv;
  v.z *= inv;
  v.w *= inv;
  ((float4*)row)[tid] = v;
  if (p16) {
    h4 hv = {(_Float16)v.x, (_Float16)v.y, (_Float16)v.z, (_Float16)v.w};
    *(h4*)(p16 + (long)blockIdx.x * SLEN + tid * 4) = hv;
  }
}

// concat[t, b, DIM + d] = input[b, t, d]  (fallback path only)
__global__ __launch_bounds__(256) void concat_copy_kernel(
    const float* __restrict__ in, float* __restrict__ concat,
    _Float16* __restrict__ c16) {
  const int bt = blockIdx.x;  // b*T + t
  const int b = bt >> 9;      // T = 512
  const int t = bt & 511;
  const float4 v = ((const float4*)(in + (long)bt * DIM))[threadIdx.x];
  const long off = ((long)t * BATCH + b) * (2 * DIM) + DIM;
  ((float4*)(concat + off))[threadIdx.x] = v;
  if (c16) {
    h4 hv = {(_Float16)v.x, (_Float16)v.y, (_Float16)v.z, (_Float16)v.w};
    *(h4*)(c16 + off + threadIdx.x * 4) = hv;
  }
}

// ---------------------------------------------------------------------------

extern "C" void kernel_launch(void* const* d_in, const int* in_sizes, int n_in,
                              void* d_out, int out_size, void* d_ws,
                              size_t ws_size, hipStream_t stream) {
  const float* input = (const float*)d_in[0];    // [B,T,D]
  const float* context = (const float*)d_in[1];  // [B,S,D]
  const float* W_in = (const float*)d_in[2];     // [D,D]
  const float* W_out = (const float*)d_in[3];    // [D,2D]

  float* out = (float*)d_out;
  float* attn_h = out;                                // [T,B,D]
  float* align = out + (long)TLEN * BATCH * DIM;      // [T,B,S]
  float* concat = align + (long)TLEN * BATCH * SLEN;  // [T,B,2D]

  const long BT = (long)BATCH * TLEN;        // 16384
  const long ND = (long)BATCH * TLEN * DIM;  // 16,777,216 elements

  // ws: ctx16 (64 MiB) + ctx16t (64 MiB) + cat16 (64 MiB) + wout16 (4 MiB)
  const size_t WS_NEED = (size_t)3 * 67108864 + 4194304;

  if (d_ws != nullptr && ws_size >= WS_NEED) {
    _Float16* ctx16 = (_Float16*)d_ws;                        // [B,S,D]
    _Float16* ctx16t = ctx16 + (long)BATCH * SLEN * DIM;      // [B,D,S]
    _Float16* cat16 = ctx16t + (long)BATCH * SLEN * DIM;      // [T,B,2D]
    _Float16* wout16 = cat16 + (long)TLEN * BATCH * 2 * DIM;  // [D,2D]
    // Carved scratch: align region dead until GEMM2; attn_h dead until GEMM4.
    _Float16* in16 = (_Float16*)align;   // [B,T,D], dies after GEMM1
    _Float16* win16 = in16 + ND;         // [D,D],   dies after GEMM1
    _Float16* ht16 = (_Float16*)attn_h;  // [B,T,D], dies after GEMM2
    _Float16* p16 = ht16 + ND;           // [T,B,S], dies after GEMM3

    cvt3<<<456, 256, 0, stream>>>(input, in16, W_in, win16, W_out, wout16);
    ctx_cvt<<<dim3(16, 16, BATCH), 256, 0, stream>>>(context, ctx16, ctx16t);

    // GEMM1 (f16 out): ht16[b*T+t, e] = sum_d in16[bt,d] * win16[e,d]
    gemm16<2><<<dim3(DIM / BN, BT / BM, 1), 256, 0, stream>>>(
        in16, win16, nullptr, ht16, DIM,
        /*lda*/ DIM, /*ldb*/ DIM, /*ldc*/ 0, /*ldc16*/ DIM, 0, 0, 0, 0,
        nullptr);

    // GEMM2 (f32 out, batched): align[t,b,s] = sum_d ht16[b,t,d]*ctx16[b,s,d]
    gemm16<0><<<dim3(SLEN / BN, TLEN / BM, BATCH), 256, 0, stream>>>(
        ht16, ctx16, align, nullptr, DIM,
        /*lda*/ DIM, /*ldb*/ DIM, /*ldc*/ (long)BATCH * SLEN, /*ldc16*/ 0,
        /*sA*/ (long)TLEN * DIM, /*sB*/ (long)SLEN * DIM, /*sC*/ SLEN, 0,
        nullptr);

    softmax_kernel<<<(int)BT, 256, 0, stream>>>(align, p16);

    // GEMM3 (f32+f16 out + concat fold): c[t,b,d] = sum_s p16*ctx16t
    gemm16<4><<<dim3(DIM / BN, TLEN / BM, BATCH), 256, 0, stream>>>(
        p16, ctx16t, concat, cat16, SLEN,
        /*lda*/ (long)BATCH * SLEN, /*ldb*/ SLEN,
        /*ldc*/ (long)BATCH * 2 * DIM, /*ldc16*/ (long)BATCH * 2 * DIM,
        /*sA*/ SLEN, /*sB*/ (long)DIM * SLEN, /*sC*/ 2 * DIM,
        /*sC16*/ 2 * DIM, input);

    // GEMM4 (f32 + tanh): attn_h[t*B+b, d] = tanh(sum_f cat16*wout16)
    gemm16<1><<<dim3(DIM / BN, BT / BM, 1), 256, 0, stream>>>(
        cat16, wout16, attn_h, nullptr, 2 * DIM,
        /*lda*/ 2 * DIM, /*ldb*/ 2 * DIM, /*ldc*/ DIM, /*ldc16*/ 0, 0, 0, 0, 0,
        nullptr);
    return;
  }

  // -------- fallback: round-0 verified fp32-operand pipeline --------
  float* h_t = attn_h;

  gemm_f16<true, false><<<dim3(DIM / BN, BT / BM, 1), 256, 0, stream>>>(
      input, W_in, h_t, (int)BT, DIM, DIM, DIM, DIM, DIM, 0, 0, 0);

  gemm_f16<true, false><<<dim3(SLEN / BN, TLEN / BM, BATCH), 256, 0, stream>>>(
      h_t, context, align, TLEN, SLEN, DIM, DIM, DIM, (long)BATCH * SLEN,
      (long)TLEN * DIM, (long)SLEN * DIM, SLEN);

  softmax_kernel<<<(int)BT, 256, 0, stream>>>(align, nullptr);

  gemm_f16<false, false><<<dim3(DIM / BN, TLEN / BM, BATCH), 256, 0, stream>>>(
      align, context, concat, TLEN, DIM, SLEN, (long)BATCH * SLEN, DIM,
      (long)BATCH * 2 * DIM, SLEN, (long)SLEN * DIM, 2 * DIM);

  concat_copy_kernel<<<(int)BT, 256, 0, stream>>>(input, concat, nullptr);

  gemm_f16<true, true><<<dim3(DIM / BN, BT / BM, 1), 256, 0, stream>>>(
      concat, W_out, attn_h, (int)BT, DIM, 2 * DIM, 2 * DIM, 2 * DIM, DIM,
      0, 0, 0);
}

// Round 3
// 710.480 us; speedup vs baseline: 1.2659x; 1.0773x over previous
//
#include <hip/hip_runtime.h>
#include <cmath>

// Problem constants: B=32, T=512, S=1024, D=1024
#define BATCH 32
#define TLEN  512
#define SLEN  1024
#define DIM   1024

typedef _Float16 h8 __attribute__((ext_vector_type(8)));
typedef _Float16 h4 __attribute__((ext_vector_type(4)));
typedef _Float16 h2 __attribute__((ext_vector_type(2)));
typedef float f4 __attribute__((ext_vector_type(4)));

__device__ __forceinline__ void gload16(const _Float16* g, _Float16* l) {
  __builtin_amdgcn_global_load_lds(
      (const __attribute__((address_space(1))) unsigned int*)g,
      (__attribute__((address_space(3))) unsigned int*)l, 16, 0, 0);
}

// ---------------------------------------------------------------------------
// FAST PATH: 256x256 8-phase fp16 NT GEMM (T2 swizzle + T3/T4 counted vmcnt
// + T5 setprio). 512 threads = 8 waves (2M x 4N), BK=64, 128 KiB LDS dbuf.
// C[m,n] = sum_k A[m,k] * B[n,k]
// EPI: 0=f32, 1=f32 tanh, 2=f16, 3=f32+f16, 4=f32+f16 + concat-copy fold
// ---------------------------------------------------------------------------

// Stage one half-tile (128 rows x 64 halfs = 16 KB): 2 global_load_lds/wave.
// Linear LDS dest (wave-uniform base + lane*16B, HW pattern); source chunk
// pre-swizzled j ^= row&7 so swizzled reads see unswizzled data (rule #21).
__device__ __forceinline__ void stage_half(
    const _Float16* __restrict__ g, long ld, int k0,
    _Float16* lds_region, int wave, int lane) {
#pragma unroll
  for (int i = 0; i < 2; ++i) {
    const int c = (i * 8 + wave) * 64 + lane;  // 16B-chunk idx in half-tile
    const int rl = c >> 3;                     // row 0..127
    const int j = (c & 7) ^ (rl & 7);          // source-side swizzle
    gload16(g + (long)rl * ld + k0 + j * 8,
            lds_region + (i * 8 + wave) * 512);
  }
}

#define SFENCE __builtin_amdgcn_sched_barrier(0)
#define SBAR   __builtin_amdgcn_s_barrier()

template <int EPI>
__global__ __launch_bounds__(512, 2) void gemm256(
    const _Float16* __restrict__ A, const _Float16* __restrict__ Bm,
    float* __restrict__ C, _Float16* __restrict__ C16, int K,
    long lda, long ldb, long ldc, long ldc16,
    long strideA, long strideB, long strideC, long strideC16,
    const float* __restrict__ Xin) {
  __shared__ _Float16 LA[2][256][64];  // 64 KiB (A halves: rows 0-127/128-255)
  __shared__ _Float16 LB[2][256][64];  // 64 KiB

  const int bz = blockIdx.z;
  A += (long)bz * strideA;
  Bm += (long)bz * strideB;

  const int m0 = blockIdx.y * 256;
  const int n0 = blockIdx.x * 256;
  const int tid = threadIdx.x;
  const int lane = tid & 63;
  const int wave = tid >> 6;  // 0..7
  const int wr = wave >> 2;   // 0..1  -> rows wr*128..+127
  const int wc = wave & 3;    // 0..3  -> cols wc*64..+63
  const int q = lane >> 4;    // k-quad
  const int r = lane & 15;    // row/col within 16

  f4 acc[8][4];
#pragma unroll
  for (int i = 0; i < 8; ++i)
#pragma unroll
    for (int j = 0; j < 4; ++j) acc[i][j] = (f4){0.f, 0.f, 0.f, 0.f};

  const int ntile = K >> 6;  // >= 2 for all our GEMMs

  // ---- prologue: tile0 fully + tile1 {B0,B1,A0} (A1 comes at t0.P1) ----
  stage_half(A + (long)m0 * lda, lda, 0, &LA[0][0][0], wave, lane);
  stage_half(A + (long)(m0 + 128) * lda, lda, 0, &LA[0][128][0], wave, lane);
  stage_half(Bm + (long)n0 * ldb, ldb, 0, &LB[0][0][0], wave, lane);
  stage_half(Bm + (long)(n0 + 128) * ldb, ldb, 0, &LB[0][128][0], wave, lane);
  if (ntile > 1) {
    stage_half(Bm + (long)n0 * ldb, ldb, 64, &LB[1][0][0], wave, lane);
    stage_half(Bm + (long)(n0 + 128) * ldb, ldb, 64, &LB[1][128][0], wave, lane);
    stage_half(A + (long)m0 * lda, lda, 64, &LA[1][0][0], wave, lane);
    asm volatile("s_waitcnt vmcnt(6)" ::: "memory");  // tile0 landed
  } else {
    asm volatile("s_waitcnt vmcnt(0)" ::: "memory");
  }
  SBAR;

  for (int t = 0; t < ntile; ++t) {
    const int p = t & 1;
    const bool s1 = (t + 1) < ntile;
    const bool s2 = (t + 2) < ntile;
    const int k1 = (t + 1) << 6;
    const int k2 = (t + 2) << 6;

    h8 a_lo[4][2], a_hi[4][2], b[4][2];

    // ======== Phase 1: read a_lo + all b; stage (t+1).A1 (other buf) ========
#pragma unroll
    for (int mt = 0; mt < 4; ++mt)
#pragma unroll
      for (int kk = 0; kk < 2; ++kk)
        a_lo[mt][kk] = *(const h8*)&LA[p][wr * 128 + mt * 16 + r]
                                      [((kk * 4 + q) ^ (r & 7)) * 8];
#pragma unroll
    for (int nn = 0; nn < 4; ++nn)
#pragma unroll
      for (int kk = 0; kk < 2; ++kk)
        b[nn][kk] = *(const h8*)&LB[p][wc * 64 + nn * 16 + r]
                                     [((kk * 4 + q) ^ (r & 7)) * 8];
    if (s1)
      stage_half(A + (long)(m0 + 128) * lda, lda, k1, &LA[p ^ 1][128][0],
                 wave, lane);
    SFENCE; SBAR;
    asm volatile("s_waitcnt lgkmcnt(0)" ::: "memory");
    SFENCE;
    __builtin_amdgcn_s_setprio(1);
#pragma unroll
    for (int mt = 0; mt < 4; ++mt)
#pragma unroll
      for (int nn = 0; nn < 2; ++nn)
#pragma unroll
        for (int kk = 0; kk < 2; ++kk)
          acc[mt][nn] = __builtin_amdgcn_mfma_f32_16x16x32_f16(
              a_lo[mt][kk], b[nn][kk], acc[mt][nn], 0, 0, 0);
    __builtin_amdgcn_s_setprio(0);
    SFENCE; SBAR;

    // ======== Phase 2: read a_hi; stage (t+2).B0 (B last read in P1) =======
#pragma unroll
    for (int mt = 0; mt < 4; ++mt)
#pragma unroll
      for (int kk = 0; kk < 2; ++kk)
        a_hi[mt][kk] = *(const h8*)&LA[p][wr * 128 + 64 + mt * 16 + r]
                                       [((kk * 4 + q) ^ (r & 7)) * 8];
    if (s2) stage_half(Bm + (long)n0 * ldb, ldb, k2, &LB[p][0][0], wave, lane);
    SFENCE; SBAR;
    asm volatile("s_waitcnt lgkmcnt(0)" ::: "memory");
    SFENCE;
    __builtin_amdgcn_s_setprio(1);
#pragma unroll
    for (int mt = 0; mt < 4; ++mt)
#pragma unroll
      for (int nn = 0; nn < 2; ++nn)
#pragma unroll
        for (int kk = 0; kk < 2; ++kk)
          acc[mt][2 + nn] = __builtin_amdgcn_mfma_f32_16x16x32_f16(
              a_lo[mt][kk], b[2 + nn][kk], acc[mt][2 + nn], 0, 0, 0);
    __builtin_amdgcn_s_setprio(0);
    SFENCE; SBAR;

    // ======== Phase 3: stage (t+2).B1 ======================================
    if (s2)
      stage_half(Bm + (long)(n0 + 128) * ldb, ldb, k2, &LB[p][128][0],
                 wave, lane);
    SFENCE; SBAR;
    asm volatile("s_waitcnt lgkmcnt(0)" ::: "memory");
    SFENCE;
    __builtin_amdgcn_s_setprio(1);
#pragma unroll
    for (int mt = 0; mt < 4; ++mt)
#pragma unroll
      for (int nn = 0; nn < 2; ++nn)
#pragma unroll
        for (int kk = 0; kk < 2; ++kk)
          acc[4 + mt][nn] = __builtin_amdgcn_mfma_f32_16x16x32_f16(
              a_hi[mt][kk], b[nn][kk], acc[4 + mt][nn], 0, 0, 0);
    __builtin_amdgcn_s_setprio(0);
    SFENCE; SBAR;

    // ======== Phase 4: stage (t+2).A0 (A last read in P2); tile-end wait ===
    if (s2) stage_half(A + (long)m0 * lda, lda, k2, &LA[p][0][0], wave, lane);
    SFENCE; SBAR;
    asm volatile("s_waitcnt lgkmcnt(0)" ::: "memory");
    SFENCE;
    __builtin_amdgcn_s_setprio(1);
#pragma unroll
    for (int mt = 0; mt < 4; ++mt)
#pragma unroll
      for (int nn = 0; nn < 2; ++nn)
#pragma unroll
        for (int kk = 0; kk < 2; ++kk)
          acc[4 + mt][2 + nn] = __builtin_amdgcn_mfma_f32_16x16x32_f16(
              a_hi[mt][kk], b[2 + nn][kk], acc[4 + mt][2 + nn], 0, 0, 0);
    __builtin_amdgcn_s_setprio(0);
    SFENCE;
    // counted drain: 3 half-tiles (6 loads) stay in flight (T4); tail -> 0
    if (s2) asm volatile("s_waitcnt vmcnt(6)" ::: "memory");
    else    asm volatile("s_waitcnt vmcnt(0)" ::: "memory");
    SBAR;
  }

  // ---- epilogue: D[row=(q*4+i)][col=r] per 16x16 tile (verified layout) ----
#pragma unroll
  for (int mt = 0; mt < 8; ++mt) {
#pragma unroll
    for (int nt = 0; nt < 4; ++nt) {
#pragma unroll
      for (int i = 0; i < 4; ++i) {
        float x = acc[mt][nt][i];
        const long row = m0 + wr * 128 + mt * 16 + q * 4 + i;
        const long col = n0 + wc * 64 + nt * 16 + r;
        if constexpr (EPI == 1) x = tanhf(x);
        if constexpr (EPI != 2)
          C[(long)bz * strideC + row * ldc + col] = x;
        if constexpr (EPI >= 2)
          C16[(long)bz * strideC16 + row * ldc16 + col] = (_Float16)x;
      }
    }
  }

  if constexpr (EPI == 4) {
    // concat fold: concat[t, b, DIM + d] = input[b, t, d] (f32 + f16),
    // for this block's 256 t-rows x 256 d-cols, batch bz.
#pragma unroll
    for (int it = 0; it < 32; ++it) {
      const int idx = it * 512 + tid;
      const int row = idx >> 6;           // 64 f4-chunks per 256-col row
      const int c4 = (idx & 63) * 4;
      const f4 v = *(const f4*)(Xin + ((long)bz * TLEN + m0 + row) * DIM +
                                n0 + c4);
      *(f4*)(C + (long)bz * strideC + (long)(m0 + row) * ldc + DIM + n0 + c4) =
          v;
      h4 hv = {(_Float16)v.x, (_Float16)v.y, (_Float16)v.z, (_Float16)v.w};
      *(h4*)(C16 + (long)bz * strideC16 + (long)(m0 + row) * ldc16 + DIM +
             n0 + c4) = hv;
    }
  }
}

// One-launch fp32->fp16 convert of input + W_in + W_out (block-range split).
__global__ __launch_bounds__(256) void cvt3(
    const float* __restrict__ in, _Float16* __restrict__ out,
    const float* __restrict__ in2, _Float16* __restrict__ out2,
    const float* __restrict__ in3, _Float16* __restrict__ out3) {
  const int b = blockIdx.x;
  const float* src;
  _Float16* dst;
  long n;
  int b0, nb;
  if (b < 384) { src = in;  dst = out;  n = 16777216; b0 = 0;   nb = 384; }
  else if (b < 408) { src = in2; dst = out2; n = 1048576; b0 = 384; nb = 24; }
  else { src = in3; dst = out3; n = 2097152; b0 = 408; nb = 48; }
  long i = ((long)(b - b0) * 256 + threadIdx.x) * 4;
  const long stride = (long)nb * 1024;
  for (; i < n; i += stride) {
    f4 v = *(const f4*)(src + i);
    h4 hv = {(_Float16)v.x, (_Float16)v.y, (_Float16)v.z, (_Float16)v.w};
    *(h4*)(dst + i) = hv;
  }
}

// context [B,S,D] fp32 -> c16 [B,S,D] fp16 + c16t [B,D,S] fp16 (transposed).
#define CTPAD 68  // multiple of 4 (h4-aligned LDS writes)
__global__ __launch_bounds__(256) void ctx_cvt(
    const float* __restrict__ ctx, _Float16* __restrict__ c16,
    _Float16* __restrict__ c16t) {
  __shared__ _Float16 tile[64 * CTPAD];
  const int b = blockIdx.z;
  const int s0 = blockIdx.y * 64;
  const int d0 = blockIdx.x * 64;
  const int tr = threadIdx.x >> 4;        // 0..15
  const int tc = (threadIdx.x & 15) * 4;  // 0..60
#pragma unroll
  for (int i = 0; i < 4; ++i) {
    const int s = i * 16 + tr;
    float4 v = *(const float4*)(ctx + ((long)b * SLEN + s0 + s) * DIM + d0 + tc);
    h4 hv = {(_Float16)v.x, (_Float16)v.y, (_Float16)v.z, (_Float16)v.w};
    *(h4*)(c16 + ((long)b * SLEN + s0 + s) * DIM + d0 + tc) = hv;
    *(h4*)&tile[s * CTPAD + tc] = hv;
  }
  __syncthreads();
#pragma unroll
  for (int i = 0; i < 4; ++i) {
    const int d = i * 16 + tr;
    h4 hv = {tile[tc * CTPAD + d], tile[(tc + 1) * CTPAD + d],
             tile[(tc + 2) * CTPAD + d], tile[(tc + 3) * CTPAD + d]};
    *(h4*)(c16t + ((long)b * DIM + d0 + d) * SLEN + s0 + tc) = hv;
  }
}

// ---------------------------------------------------------------------------
// FALLBACK PATH (verified round-0 kernel): fp32-operand convert-at-staging.
// ---------------------------------------------------------------------------

#define FBM 128
#define AS_LD 40   // BK + 8 pad halfs
#define B2_LD 134  // BN + 6 pad halfs
#define BKF 32

template <bool B_IS_NT, bool TANH>
__global__ __launch_bounds__(256) void gemm_f16(
    const float* __restrict__ A, const float* __restrict__ Bm,
    float* __restrict__ C, int M, int N, int K, long lda, long ldb, long ldc,
    long strideA, long strideB, long strideC) {
  __shared__ _Float16 As[FBM * AS_LD];
  __shared__ _Float16 Bs[FBM * AS_LD];

  const int bz = blockIdx.z;
  A += (long)bz * strideA;
  Bm += (long)bz * strideB;
  C += (long)bz * strideC;

  const int m0 = blockIdx.y * FBM;
  const int n0 = blockIdx.x * FBM;
  const int tid = threadIdx.x;
  const int lane = tid & 63;
  const int wave = tid >> 6;
  const int wm = (wave >> 1) * 64;
  const int wn = (wave & 1) * 64;
  const int q = lane >> 4;
  const int r = lane & 15;

  f4 acc[4][4];
#pragma unroll
  for (int i = 0; i < 4; ++i)
#pragma unroll
    for (int j = 0; j < 4; ++j) acc[i][j] = (f4){0.f, 0.f, 0.f, 0.f};

  const int srow = tid >> 3;
  const int skq = (tid & 7) * 4;
  const int nrow = tid >> 5;
  const int nnq = (tid & 31) * 4;

  for (int k0 = 0; k0 < K; k0 += BKF) {
#pragma unroll
    for (int it = 0; it < 4; ++it) {
      const int row = it * 32 + srow;
      f4 v = *(const f4*)(A + (long)(m0 + row) * lda + k0 + skq);
      h4 hv = {(_Float16)v.x, (_Float16)v.y, (_Float16)v.z, (_Float16)v.w};
      *(h4*)&As[row * AS_LD + skq] = hv;
    }
    if (B_IS_NT) {
#pragma unroll
      for (int it = 0; it < 4; ++it) {
        const int row = it * 32 + srow;
        f4 v = *(const f4*)(Bm + (long)(n0 + row) * ldb + k0 + skq);
        h4 hv = {(_Float16)v.x, (_Float16)v.y, (_Float16)v.z, (_Float16)v.w};
        *(h4*)&Bs[row * AS_LD + skq] = hv;
      }
    } else {
#pragma unroll
      for (int it = 0; it < 4; ++it) {
        const int krow = it * 8 + nrow;
        f4 v = *(const f4*)(Bm + (long)(k0 + krow) * ldb + n0 + nnq);
        _Float16* p = &Bs[krow * B2_LD + nnq];
        *(h2*)p = (h2){(_Float16)v.x, (_Float16)v.y};
        *(h2*)(p + 2) = (h2){(_Float16)v.z, (_Float16)v.w};
      }
    }
    __syncthreads();

    h8 av[4], bv[4];
#pragma unroll
    for (int mt = 0; mt < 4; ++mt)
      av[mt] = *(const h8*)&As[(wm + mt * 16 + r) * AS_LD + q * 8];
    if (B_IS_NT) {
#pragma unroll
      for (int nt = 0; nt < 4; ++nt)
        bv[nt] = *(const h8*)&Bs[(wn + nt * 16 + r) * AS_LD + q * 8];
    } else {
#pragma unroll
      for (int nt = 0; nt < 4; ++nt) {
        h8 tv;
#pragma unroll
        for (int j = 0; j < 8; ++j)
          tv[j] = Bs[(q * 8 + j) * B2_LD + wn + nt * 16 + r];
        bv[nt] = tv;
      }
    }
#pragma unroll
    for (int mt = 0; mt < 4; ++mt)
#pragma unroll
      for (int nt = 0; nt < 4; ++nt)
        acc[mt][nt] = __builtin_amdgcn_mfma_f32_16x16x32_f16(
            av[mt], bv[nt], acc[mt][nt], 0, 0, 0);
    __syncthreads();
  }

#pragma unroll
  for (int mt = 0; mt < 4; ++mt) {
#pragma unroll
    for (int nt = 0; nt < 4; ++nt) {
#pragma unroll
      for (int i = 0; i < 4; ++i) {
        float x = acc[mt][nt][i];
        if (TANH) x = tanhf(x);
        C[(long)(m0 + wm + mt * 16 + q * 4 + i) * ldc + n0 + wn + nt * 16 + r] = x;
      }
    }
  }
}

// ---------------------------------------------------------------------------
// Shared auxiliary kernels
// ---------------------------------------------------------------------------

// In-place softmax over rows of length 1024; optional fp16 dual-write.
__global__ __launch_bounds__(256) void softmax_kernel(
    float* __restrict__ data, _Float16* __restrict__ p16) {
  float* row = data + (long)blockIdx.x * SLEN;
  const int tid = threadIdx.x;
  float4 v = ((float4*)row)[tid];
  float m = fmaxf(fmaxf(v.x, v.y), fmaxf(v.z, v.w));
#pragma unroll
  for (int off = 32; off > 0; off >>= 1) m = fmaxf(m, __shfl_xor(m, off));
  __shared__ float redm[4];
  __shared__ float reds[4];
  if ((tid & 63) == 0) redm[tid >> 6] = m;
  __syncthreads();
  m = fmaxf(fmaxf(redm[0], redm[1]), fmaxf(redm[2], redm[3]));
  v.x = expf(v.x - m);
  v.y = expf(v.y - m);
  v.z = expf(v.z - m);
  v.w = expf(v.w - m);
  float s = v.x + v.y + v.z + v.w;
#pragma unroll
  for (int off = 32; off > 0; off >>= 1) s += __shfl_xor(s, off);
  if ((tid & 63) == 0) reds[tid >> 6] = s;
  __syncthreads();
  s = reds[0] + reds[1] + reds[2] + reds[3];
  const float inv = 1.0f / s;
  v.x *= inv;
  v.y *= inv;
  v.z *= inv;
  v.w *= inv;
  ((float4*)row)[tid] = v;
  if (p16) {
    h4 hv = {(_Float16)v.x, (_Float16)v.y, (_Float16)v.z, (_Float16)v.w};
    *(h4*)(p16 + (long)blockIdx.x * SLEN + tid * 4) = hv;
  }
}

// concat[t, b, DIM + d] = input[b, t, d]  (fallback path only)
__global__ __launch_bounds__(256) void concat_copy_kernel(
    const float* __restrict__ in, float* __restrict__ concat,
    _Float16* __restrict__ c16) {
  const int bt = blockIdx.x;  // b*T + t
  const int b = bt >> 9;      // T = 512
  const int t = bt & 511;
  const float4 v = ((const float4*)(in + (long)bt * DIM))[threadIdx.x];
  const long off = ((long)t * BATCH + b) * (2 * DIM) + DIM;
  ((float4*)(concat + off))[threadIdx.x] = v;
  if (c16) {
    h4 hv = {(_Float16)v.x, (_Float16)v.y, (_Float16)v.z, (_Float16)v.w};
    *(h4*)(c16 + off + threadIdx.x * 4) = hv;
  }
}

// ---------------------------------------------------------------------------

extern "C" void kernel_launch(void* const* d_in, const int* in_sizes, int n_in,
                              void* d_out, int out_size, void* d_ws,
                              size_t ws_size, hipStream_t stream) {
  const float* input = (const float*)d_in[0];    // [B,T,D]
  const float* context = (const float*)d_in[1];  // [B,S,D]
  const float* W_in = (const float*)d_in[2];     // [D,D]
  const float* W_out = (const float*)d_in[3];    // [D,2D]

  float* out = (float*)d_out;
  float* attn_h = out;                                // [T,B,D]
  float* align = out + (long)TLEN * BATCH * DIM;      // [T,B,S]
  float* concat = align + (long)TLEN * BATCH * SLEN;  // [T,B,2D]

  const long BT = (long)BATCH * TLEN;        // 16384
  const long ND = (long)BATCH * TLEN * DIM;  // 16,777,216 elements

  // ws: ctx16 (64 MiB) + ctx16t (64 MiB) + cat16 (64 MiB) + wout16 (4 MiB)
  const size_t WS_NEED = (size_t)3 * 67108864 + 4194304;

  if (d_ws != nullptr && ws_size >= WS_NEED) {
    _Float16* ctx16 = (_Float16*)d_ws;                        // [B,S,D]
    _Float16* ctx16t = ctx16 + (long)BATCH * SLEN * DIM;      // [B,D,S]
    _Float16* cat16 = ctx16t + (long)BATCH * SLEN * DIM;      // [T,B,2D]
    _Float16* wout16 = cat16 + (long)TLEN * BATCH * 2 * DIM;  // [D,2D]
    // Carved scratch: align region dead until GEMM2; attn_h dead until GEMM4.
    _Float16* in16 = (_Float16*)align;   // [B,T,D], dies after GEMM1
    _Float16* win16 = in16 + ND;         // [D,D],   dies after GEMM1
    _Float16* ht16 = (_Float16*)attn_h;  // [B,T,D], dies after GEMM2
    _Float16* p16 = ht16 + ND;           // [T,B,S], dies after GEMM3

    cvt3<<<456, 256, 0, stream>>>(input, in16, W_in, win16, W_out, wout16);
    ctx_cvt<<<dim3(16, 16, BATCH), 256, 0, stream>>>(context, ctx16, ctx16t);

    // GEMM1 (f16 out): ht16[b*T+t, e] = sum_d in16[bt,d] * win16[e,d]
    gemm256<2><<<dim3(DIM / 256, BT / 256, 1), 512, 0, stream>>>(
        in16, win16, nullptr, ht16, DIM,
        /*lda*/ DIM, /*ldb*/ DIM, /*ldc*/ 0, /*ldc16*/ DIM, 0, 0, 0, 0,
        nullptr);

    // GEMM2 (f32 out, batched): align[t,b,s] = sum_d ht16[b,t,d]*ctx16[b,s,d]
    gemm256<0><<<dim3(SLEN / 256, TLEN / 256, BATCH), 512, 0, stream>>>(
        ht16, ctx16, align, nullptr, DIM,
        /*lda*/ DIM, /*ldb*/ DIM, /*ldc*/ (long)BATCH * SLEN, /*ldc16*/ 0,
        /*sA*/ (long)TLEN * DIM, /*sB*/ (long)SLEN * DIM, /*sC*/ SLEN, 0,
        nullptr);

    softmax_kernel<<<(int)BT, 256, 0, stream>>>(align, p16);

    // GEMM3 (f32+f16 out + concat fold): c[t,b,d] = sum_s p16*ctx16t
    gemm256<4><<<dim3(DIM / 256, TLEN / 256, BATCH), 512, 0, stream>>>(
        p16, ctx16t, concat, cat16, SLEN,
        /*lda*/ (long)BATCH * SLEN, /*ldb*/ SLEN,
        /*ldc*/ (long)BATCH * 2 * DIM, /*ldc16*/ (long)BATCH * 2 * DIM,
        /*sA*/ SLEN, /*sB*/ (long)DIM * SLEN, /*sC*/ 2 * DIM,
        /*sC16*/ 2 * DIM, input);

    // GEMM4 (f32 + tanh): attn_h[t*B+b, d] = tanh(sum_f cat16*wout16)
    gemm256<1><<<dim3(DIM / 256, BT / 256, 1), 512, 0, stream>>>(
        cat16, wout16, attn_h, nullptr, 2 * DIM,
        /*lda*/ 2 * DIM, /*ldb*/ 2 * DIM, /*ldc*/ DIM, /*ldc16*/ 0, 0, 0, 0, 0,
        nullptr);
    return;
  }

  // -------- fallback: round-0 verified fp32-operand pipeline --------
  float* h_t = attn_h;

  gemm_f16<true, false><<<dim3(DIM / FBM, BT / FBM, 1), 256, 0, stream>>>(
      input, W_in, h_t, (int)BT, DIM, DIM, DIM, DIM, DIM, 0, 0, 0);

  gemm_f16<true, false><<<dim3(SLEN / FBM, TLEN / FBM, BATCH), 256, 0, stream>>>(
      h_t, context, align, TLEN, SLEN, DIM, DIM, DIM, (long)BATCH * SLEN,
      (long)TLEN * DIM, (long)SLEN * DIM, SLEN);

  softmax_kernel<<<(int)BT, 256, 0, stream>>>(align, nullptr);

  gemm_f16<false, false><<<dim3(DIM / FBM, TLEN / FBM, BATCH), 256, 0, stream>>>(
      align, context, concat, TLEN, DIM, SLEN, (long)BATCH * SLEN, DIM,
      (long)BATCH * 2 * DIM, SLEN, (long)SLEN * DIM, 2 * DIM);

  concat_copy_kernel<<<(int)BT, 256, 0, stream>>>(input, concat, nullptr);

  gemm_f16<true, true><<<dim3(DIM / FBM, BT / FBM, 1), 256, 0, stream>>>(
      concat, W_out, attn_h, (int)BT, DIM, 2 * DIM, 2 * DIM, 2 * DIM, DIM,
      0, 0, 0);
}